// Round 2
// baseline (260.592 us; speedup 1.0000x reference)
//
#include <hip/hip_runtime.h>

// Problem constants (from reference)
#define VOCAB   35097
#define DDIM    300
#define NWORDS  3000
#define L_SIG   900000          // DDIM * NWORDS
#define NFILT   100
#define NCLS    10

// Tiling: QQ positions per lane (multiple of 4, even for max3 pairing)
#define QQ      32
#define BLK_POS (64 * QQ)       // 2048 positions per block
#define NBLK    440             // ceil(899998 / 2048)

__device__ __forceinline__ float relu_(float v) { return fmaxf(v, 0.0f); }

// Each wave handles 25 filters x 3 conv sizes over the block's position tile.
// Inner loop tracks the RAW conv max (bias+ReLU deferred: both monotone, so
// relu(max(conv)+b) == max(relu(conv+b))). TAIL path masks positions past the
// valid range (only the last blockIdx.x takes it).
template<bool TAIL>
__device__ __forceinline__ void run_filters(
    const float (&h)[QQ + 4], int t0, int wave, int batch, int lane,
    const float* __restrict__ w1, const float* __restrict__ b1,
    const float* __restrict__ w2, const float* __restrict__ b2,
    const float* __restrict__ w3, const float* __restrict__ b3,
    unsigned int* __restrict__ acc)
{
  int n3 = QQ, n4 = QQ, n5 = QQ;
  if (TAIL) {
    n3 = min(max(899998 - t0, 0), QQ);   // conv3 valid t <= 899997
    n4 = min(max(899997 - t0, 0), QQ);   // conv4 valid t <= 899996
    n5 = min(max(899996 - t0, 0), QQ);   // conv5 valid t <= 899995
  }
  const float NEG = -__builtin_huge_valf();

  #pragma unroll 1   // one copy of the (fully unrolled) p-loop body
  for (int i = 0; i < 25; ++i) {
    const int f = wave * 25 + i;
    const float a0 = w1[f*3+0], a1 = w1[f*3+1], a2 = w1[f*3+2];
    const float c0 = w2[f*4+0], c1 = w2[f*4+1], c2 = w2[f*4+2], c3 = w2[f*4+3];
    const float e0 = w3[f*5+0], e1 = w3[f*5+1], e2 = w3[f*5+2], e3 = w3[f*5+3], e4 = w3[f*5+4];

    // two alternating accumulators per conv -> short dependent max chains
    float m3[2] = {NEG, NEG}, m4[2] = {NEG, NEG}, m5[2] = {NEG, NEG};

    if (!TAIL) {
      // Pairs of positions; fmaxf(fmaxf(m,va),vb) fuses to v_max3_f32.
      #pragma unroll
      for (int p = 0; p < QQ; p += 2) {
        const int q = (p >> 1) & 1;
        float v3a = fmaf(a0, h[p],   fmaf(a1, h[p+1], a2 * h[p+2]));
        float v3b = fmaf(a0, h[p+1], fmaf(a1, h[p+2], a2 * h[p+3]));
        m3[q] = fmaxf(fmaxf(m3[q], v3a), v3b);
        float v4a = fmaf(c0, h[p],   fmaf(c1, h[p+1], fmaf(c2, h[p+2], c3 * h[p+3])));
        float v4b = fmaf(c0, h[p+1], fmaf(c1, h[p+2], fmaf(c2, h[p+3], c3 * h[p+4])));
        m4[q] = fmaxf(fmaxf(m4[q], v4a), v4b);
        float v5a = fmaf(e0, h[p],   fmaf(e1, h[p+1], fmaf(e2, h[p+2], fmaf(e3, h[p+3], e4 * h[p+4]))));
        float v5b = fmaf(e0, h[p+1], fmaf(e1, h[p+2], fmaf(e2, h[p+3], fmaf(e3, h[p+4], e4 * h[p+5]))));
        m5[q] = fmaxf(fmaxf(m5[q], v5a), v5b);
      }
    } else {
      #pragma unroll
      for (int p = 0; p < QQ; ++p) {
        const int q = p & 1;
        float v3 = fmaf(a0, h[p], fmaf(a1, h[p+1], a2 * h[p+2]));
        float v4 = fmaf(c0, h[p], fmaf(c1, h[p+1], fmaf(c2, h[p+2], c3 * h[p+3])));
        float v5 = fmaf(e0, h[p], fmaf(e1, h[p+1], fmaf(e2, h[p+2], fmaf(e3, h[p+3], e4 * h[p+4]))));
        if (p < n3) m3[q] = fmaxf(m3[q], v3);
        if (p < n4) m4[q] = fmaxf(m4[q], v4);
        if (p < n5) m5[q] = fmaxf(m5[q], v5);
      }
    }
    float r3 = fmaxf(m3[0], m3[1]);
    float r4 = fmaxf(m4[0], m4[1]);
    float r5 = fmaxf(m5[0], m5[1]);

    // wave-level max reduce (64 lanes)
    #pragma unroll
    for (int s = 1; s < 64; s <<= 1) {
      r3 = fmaxf(r3, __shfl_xor(r3, s));
      r4 = fmaxf(r4, __shfl_xor(r4, s));
      r5 = fmaxf(r5, __shfl_xor(r5, s));
    }
    if (lane == 0) {
      unsigned int* ab = acc + batch * 3 * NFILT;
      // post-ReLU values are >= 0 -> uint bit pattern is order-preserving
      atomicMax(ab + f,             __float_as_uint(relu_(r3 + b1[f])));
      atomicMax(ab + NFILT + f,     __float_as_uint(relu_(r4 + b2[f])));
      atomicMax(ab + 2 * NFILT + f, __float_as_uint(relu_(r5 + b3[f])));
    }
  }
}

__global__ __launch_bounds__(256) void conv_max_kernel(
    const int* __restrict__ x, const float* __restrict__ emb,
    const float* __restrict__ w1, const float* __restrict__ b1,
    const float* __restrict__ w2, const float* __restrict__ b2,
    const float* __restrict__ w3, const float* __restrict__ b3,
    unsigned int* __restrict__ acc)
{
  const int lane  = threadIdx.x & 63;
  const int wave  = threadIdx.x >> 6;
  const int batch = blockIdx.y;
  const int t0    = blockIdx.x * BLK_POS + lane * QQ;

  // Gather the signal window [t0, t0+QQ+4) directly from emb.
  // t0 % 4 == 0 and DDIM % 4 == 0 -> every segment is float4-aligned, and a
  // window of QQ+4 <= 300 floats spans at most 2 embedding rows.
  float h[QQ + 4];
  {
    int w0 = t0 / DDIM;
    int d0 = t0 - w0 * DDIM;                 // 0..296, multiple of 4
    int wa = min(w0, NWORDS - 1);            // clamp: OOB lanes masked in TAIL path
    int wb = min(w0 + 1, NWORDS - 1);
    int xa = x[batch * NWORDS + wa];
    int xb = x[batch * NWORDS + wb];
    const float4* rowA = (const float4*)(emb + (size_t)xa * DDIM) + (d0 >> 2);
    const float4* rowB = (const float4*)(emb + (size_t)xb * DDIM);
    const int nf4 = (DDIM - d0) >> 2;        // float4s remaining in word A
    #pragma unroll
    for (int i = 0; i < (QQ + 4) / 4; ++i) {
      const float4* src = (i < nf4) ? (rowA + i) : (rowB + (i - nf4));
      float4 v = *src;
      h[4*i+0] = v.x; h[4*i+1] = v.y; h[4*i+2] = v.z; h[4*i+3] = v.w;
    }
  }

  if (blockIdx.x == NBLK - 1)
    run_filters<true >(h, t0, wave, batch, lane, w1, b1, w2, b2, w3, b3, acc);
  else
    run_filters<false>(h, t0, wave, batch, lane, w1, b1, w2, b2, w3, b3, acc);
}

// out[b][c] = sum_j feats[b][j] * fc_w[c][j] + fc_b[c];  feats = relu'd maxes in acc
__global__ void fc_kernel(const unsigned int* __restrict__ acc,
                          const float* __restrict__ fcw,
                          const float* __restrict__ fcb,
                          float* __restrict__ out)
{
  const int b = blockIdx.x / NCLS;
  const int c = blockIdx.x % NCLS;
  const int lane = threadIdx.x;
  float s = 0.0f;
  for (int j = lane; j < 3 * NFILT; j += 64)
    s += __uint_as_float(acc[b * 3 * NFILT + j]) * fcw[c * 3 * NFILT + j];
  #pragma unroll
  for (int k = 1; k < 64; k <<= 1) s += __shfl_xor(s, k);
  if (lane == 0) out[b * NCLS + c] = s + fcb[c];
}

extern "C" void kernel_launch(void* const* d_in, const int* in_sizes, int n_in,
                              void* d_out, int out_size, void* d_ws, size_t ws_size,
                              hipStream_t stream)
{
  const int*   x   = (const int*)  d_in[0];
  const float* emb = (const float*)d_in[1];
  const float* w1  = (const float*)d_in[2];
  const float* b1  = (const float*)d_in[3];
  const float* w2  = (const float*)d_in[4];
  const float* b2  = (const float*)d_in[5];
  const float* w3  = (const float*)d_in[6];
  const float* b3  = (const float*)d_in[7];
  const float* fcw = (const float*)d_in[8];
  const float* fcb = (const float*)d_in[9];
  float* out = (float*)d_out;

  unsigned int* acc = (unsigned int*)d_ws;   // [2][3][100] relu'd maxes as uint bits

  // ReLU output >= 0, so 0-init is the identity for the uint atomicMax.
  hipMemsetAsync(acc, 0, 2 * 3 * NFILT * sizeof(unsigned int), stream);

  dim3 grid(NBLK, 2);
  conv_max_kernel<<<grid, 256, 0, stream>>>(x, emb, w1, b1, w2, b2, w3, b3, acc);
  fc_kernel<<<2 * NCLS, 64, 0, stream>>>(acc, fcw, fcb, out);
}